// Round 7
// baseline (514.644 us; speedup 1.0000x reference)
//
#include <hip/hip_runtime.h>

typedef unsigned short u16;
typedef unsigned int u32;
typedef __attribute__((ext_vector_type(8))) short bfrag;     // 8 bf16 (4 VGPRs) MFMA A/B
typedef __attribute__((ext_vector_type(4))) float ffrag;     // 4 f32 MFMA C/D
typedef __attribute__((ext_vector_type(4))) float f4;
typedef __attribute__((ext_vector_type(2))) float f2;        // clang vector: ok for nontemporal builtins
typedef __attribute__((ext_vector_type(2))) u32 u32x2;
typedef __attribute__((ext_vector_type(4))) int i4;

#define NVERT 35709
#define NFACE 70789
#define NV3   107127
#define NB    128

// ---- workspace byte layout ----
// Batch-minor: slab = b>>3 (16 slabs), bi = b&7 innermost.
#define SHAPE_OFF 0ull            // f32 shpT[slab][j][bi]        (54,849,024 B)  j = v*3+c
#define TEX4_OFF  54849024ull     // u16 tex4[slab][v][bi][4]     (36,566,016 B)  (x,y,z,pad) bf16 bits
#define FXY_OFF   91415040ull     // u32 fxy[slab][f][bi]         (36,243,968 B)  fn (x|y<<16) f16 bits
#define FZ_OFF    127659008ull    // u16 fz [slab][f][bi]         (18,121,984 B)  fn z f16 bits
#define CPACK_OFF 145780992ull    // u16 bf16, NB*256 padded coeffs [id80|0*16|ex64|tex80|0*16]
#define MPAD_OFF  145846528ull    // f32 [128][12]: M[0..8], T[9..11]
#define GG_OFF    145852672ull    // f32 [128][27]: G[cc*3+d]
#define MEAN_OFF  145866496ull    // f32, 3 (+1 pad)
#define PART_OFF  145866512ull    // f32, 64*3 partial sums for mean

// ---- output element offsets (f32 out) ----
#define LMS_BASE  13712256ull     // after face_color (B*NV*3)
#define ST_BASE   13729664ull     // after lms (B*68*2)

__device__ __forceinline__ float b2f(u16 s) {
  union { unsigned u; float f; } v; v.u = ((unsigned)s) << 16; return v.f;
}
__device__ __forceinline__ u16 f2b(float x) {  // f32 -> bf16 RNE
  union { float f; unsigned u; } v; v.f = x;
  unsigned r = v.u + 0x7FFFu + ((v.u >> 16) & 1u);
  return (u16)(r >> 16);
}
__device__ __forceinline__ u16 h2b(float x) {  // f32 -> f16 bits
  union { _Float16 h; u16 u; } v; v.h = (_Float16)x; return v.u;
}
__device__ __forceinline__ float hb2f(u16 u) { // f16 bits -> f32
  union { _Float16 h; u16 u2; } v; v.u2 = u; return (float)v.h;
}
__device__ __forceinline__ f4 ld4u(const float* p) {  // 16 B load, 4 B aligned
  f4 r; __builtin_memcpy(&r, p, 16); return r;
}
__device__ __forceinline__ bfrag cvt8c(const float* p) {  // 8 f32 (cached) -> 8 bf16
  f4 a = *(const f4*)p;
  f4 b = *(const f4*)(p + 4);
  bfrag r;
  r[0] = (short)f2b(a.x); r[1] = (short)f2b(a.y); r[2] = (short)f2b(a.z); r[3] = (short)f2b(a.w);
  r[4] = (short)f2b(b.x); r[5] = (short)f2b(b.y); r[6] = (short)f2b(b.z); r[7] = (short)f2b(b.w);
  return r;
}

// K0: partial sums of meanshape over vertices (64 blocks x 3 comps)
__global__ __launch_bounds__(256) void k_mean(const float* __restrict__ ms, float* __restrict__ part) {
  __shared__ float s[3];
  if (threadIdx.x < 3) s[threadIdx.x] = 0.f;
  __syncthreads();
  float a0 = 0.f, a1 = 0.f, a2 = 0.f;
  for (int v = blockIdx.x * 256 + threadIdx.x; v < NVERT; v += 64 * 256) {
    a0 += ms[v * 3 + 0];
    a1 += ms[v * 3 + 1];
    a2 += ms[v * 3 + 2];
  }
  atomicAdd(&s[0], a0); atomicAdd(&s[1], a1); atomicAdd(&s[2], a2);
  __syncthreads();
  if (threadIdx.x < 3) part[blockIdx.x * 3 + threadIdx.x] = s[threadIdx.x];
}

// K1: finalize mean; per-batch params: cpack bf16 coeffs, mpad[b][12] = M[9]+T[3], G[b][27]
__global__ __launch_bounds__(128) void k_params(const float* __restrict__ coeff, u16* __restrict__ cpack,
                                                float* __restrict__ mpad, float* __restrict__ G,
                                                const float* __restrict__ part, float* __restrict__ mean) {
  int b = threadIdx.x;
  if (b < 3) {
    float s = 0.f;
    for (int i = 0; i < 64; i++) s += part[i * 3 + b];
    mean[b] = s * (1.0f / (float)NVERT);
  }
  const float* c = coeff + b * 257;
  u16* cp = cpack + b * 256;
  for (int k = 0; k < 80; k++) cp[k] = f2b(c[k]);            // id
  for (int k = 80; k < 96; k++) cp[k] = 0;                   // pad
  for (int k = 0; k < 64; k++) cp[96 + k] = f2b(c[80 + k]);  // ex
  for (int k = 0; k < 80; k++) cp[160 + k] = f2b(c[144 + k]);// tex
  for (int k = 240; k < 256; k++) cp[k] = 0;                 // pad
  float ax = c[224], ay = c[225], az = c[226];
  float sx = sinf(ax), cx = cosf(ax);
  float sy = sinf(ay), cy = cosf(ay);
  float sz = sinf(az), cz = cosf(az);
  float* mp = mpad + b * 12;
  mp[0] = cz * cy;  mp[1] = cz * sy * sx - sz * cx;  mp[2] = sz * sx + cz * sy * cx;
  mp[3] = sz * cy;  mp[4] = cz * cx + sz * sy * sx;  mp[5] = sz * sy * cx - cz * sx;
  mp[6] = -sy;      mp[7] = cy * sx;                 mp[8] = cy * cx;
  mp[9] = c[254]; mp[10] = c[255]; mp[11] = c[256];
  float* g = G + b * 27;
  for (int cc = 0; cc < 9; cc++)
    for (int d = 0; d < 3; d++)
      g[cc * 3 + d] = c[227 + d * 9 + cc] + (cc == 0 ? 0.8f : 0.0f);
}

// K2a: shape GEMM. Wave owns 48 j = 16 vertices (3 MFMA tiles). B-frags are RELOADED per bt
// (L2-hot after first bt) so only 1 frag is live at a time -> VGPR <= 64 -> 8-waves/SIMD tier.
// `#pragma unroll 1` + per-iter memory clobber stop the compiler re-hoisting the loads.
#define SBLK 558   // ceil(NV3 / 192)
__global__ __launch_bounds__(256, 8) void k_gemmS(const float* __restrict__ idB, const float* __restrict__ exB,
                                                  const float* __restrict__ ms, const u16* __restrict__ cpack,
                                                  const float* __restrict__ meanc, const float* __restrict__ mpad,
                                                  float* __restrict__ shp, float* __restrict__ out) {
  __shared__ float SW[4][2][480];   // [wave][window s][48 j * 10]
  int jblk = blockIdx.x % SBLK, split = blockIdx.x / SBLK;
  int wave = threadIdx.x >> 6, lane = threadIdx.x & 63;
  int col = lane & 15, quad = lane >> 4;
  int jb = (jblk * 4 + wave) * 48;
  bfrag z8 = {0, 0, 0, 0, 0, 0, 0, 0};
  int jcs[3];
  float msub[3];
#pragma unroll
  for (int T = 0; T < 3; T++) {
    int j = jb + T * 16 + col;
    int jc = j < NV3 ? j : NV3 - 1;
    jcs[T] = jc;
    msub[T] = ms[jc] - meanc[jc % 3];
  }
  float (*SWl)[480] = SW[wave];
  int s0 = quad >> 1;
  int rb = (quad & 1) << 2;
  int vb = jb / 3;
  int ilim = NV3 - jb; ilim = (ilim > 48 ? 48 : ilim) * 8;
  int vlim = NVERT - vb; vlim = vlim > 16 ? 16 : vlim;

#pragma unroll 1
  for (int bt = split * 4; bt < split * 4 + 4; bt++) {
    asm volatile("" ::: "memory");   // keep B-frag loads in-loop (no LICM re-hoist)
    const u16* cp = cpack + (size_t)(bt * 16 + col) * 256;
#pragma unroll
    for (int T = 0; T < 3; T++) {
      int jc = jcs[T];
      const float* rowI = idB + (size_t)jc * 80;
      const float* rowE = exB + (size_t)jc * 64;
      ffrag acc = {0.f, 0.f, 0.f, 0.f};
#pragma unroll
      for (int f = 0; f < 3; f++) {
        int k = f * 32 + quad * 8;
        bool ok = (k < 80);
        int ks = ok ? k : 0;
        bfrag bb = cvt8c(rowI + ks);
        bb = ok ? bb : z8;
        bfrag a = *(const bfrag*)(cp + f * 32 + quad * 8);
        acc = __builtin_amdgcn_mfma_f32_16x16x32_bf16(a, bb, acc, 0, 0, 0);
      }
#pragma unroll
      for (int f = 0; f < 2; f++) {
        bfrag bb = cvt8c(rowE + f * 32 + quad * 8);
        bfrag a = *(const bfrag*)(cp + 96 + f * 32 + quad * 8);
        acc = __builtin_amdgcn_mfma_f32_16x16x32_bf16(a, bb, acc, 0, 0, 0);
      }
#pragma unroll
      for (int rr = 0; rr < 2; rr++) {
        f2 v2;
        v2.x = acc[2 * rr] + msub[T];
        v2.y = acc[2 * rr + 1] + msub[T];
        *(f2*)&SWl[s0][(T * 16 + col) * 10 + rb + 2 * rr] = v2;
      }
    }
    // raw shpT copy (coalesced; padded LDS -> addr = j*10 + bi)
#pragma unroll
    for (int s = 0; s < 2; s++) {
      size_t sb = (size_t)(bt * 2 + s) * (size_t)(NV3 * 8) + (size_t)jb * 8;
#pragma unroll
      for (int it = 0; it < 3; it++) {
        int i = it * 128 + lane * 2;
        if (i < ilim) {
          f2 vv = *(f2*)&SWl[s][(i >> 3) * 10 + (i & 7)];
          __builtin_nontemporal_store(vv, (f2*)(shp + sb + i));
        }
      }
    }
    // rotated shape_t -> out
#pragma unroll
    for (int s = 0; s < 2; s++) {
#pragma unroll
      for (int kk = 0; kk < 2; kk++) {
        int bi = (lane >> 4) + (kk << 2);
        int vloc = lane & 15;
        int b = bt * 16 + s * 8 + bi;
        float x = SWl[s][vloc * 30 + bi];
        float y = SWl[s][vloc * 30 + 10 + bi];
        float z = SWl[s][vloc * 30 + 20 + bi];
        const float* mp = mpad + b * 12;
        f4 m0 = *(const f4*)mp;
        f4 m1 = *(const f4*)(mp + 4);
        f4 m2 = *(const f4*)(mp + 8);
        if (vloc < vlim) {
          float ox = x * m0.x + y * m0.y + z * m0.z + m2.y;
          float oy = x * m0.w + y * m1.x + z * m1.y + m2.z;
          float oz = x * m1.z + y * m1.w + z * m2.x + m2.w;
          size_t o = ST_BASE + (size_t)b * NV3 + (size_t)(vb + vloc) * 3;
          __builtin_nontemporal_store(ox, out + o);
          __builtin_nontemporal_store(oy, out + o + 1);
          __builtin_nontemporal_store(oz, out + o + 2);
        }
      }
    }
  }
}

// K2b: tex GEMM, vertex-owning 48-j waves -> tex4[slab][v][bi][4] u16 padded records.
// Same per-bt frag reload + VGPR cap.
__global__ __launch_bounds__(256, 8) void k_gemmT(const float* __restrict__ txB, const float* __restrict__ mt,
                                                  const u16* __restrict__ cpack, u32* __restrict__ tex4) {
  __shared__ u16 TW[4][2][480];   // [wave][window s][48 j * 10]
  int jblk = blockIdx.x % SBLK, split = blockIdx.x / SBLK;
  int wave = threadIdx.x >> 6, lane = threadIdx.x & 63;
  int col = lane & 15, quad = lane >> 4;
  int jb = (jblk * 4 + wave) * 48;
  bfrag z8 = {0, 0, 0, 0, 0, 0, 0, 0};
  int jcs[3];
  float mtj[3];
#pragma unroll
  for (int T = 0; T < 3; T++) {
    int j = jb + T * 16 + col;
    int jc = j < NV3 ? j : NV3 - 1;
    jcs[T] = jc;
    mtj[T] = mt[jc];
  }
  u16 (*TWl)[480] = TW[wave];
  int s0 = quad >> 1;
  int rb = (quad & 1) << 2;
  int vb = jb / 3;
  int vlim = NVERT - vb; vlim = vlim > 16 ? 16 : vlim;

#pragma unroll 1
  for (int bt = split * 4; bt < split * 4 + 4; bt++) {
    asm volatile("" ::: "memory");   // keep B-frag loads in-loop
    const u16* cp = cpack + (size_t)(bt * 16 + col) * 256;
#pragma unroll
    for (int T = 0; T < 3; T++) {
      int jc = jcs[T];
      const float* rowT = txB + (size_t)jc * 80;
      ffrag acc = {0.f, 0.f, 0.f, 0.f};
#pragma unroll
      for (int f = 0; f < 3; f++) {
        int k = f * 32 + quad * 8;
        bool ok = (k < 80);
        int ks = ok ? k : 0;
        bfrag bb = cvt8c(rowT + ks);
        bb = ok ? bb : z8;
        bfrag a = *(const bfrag*)(cp + 160 + f * 32 + quad * 8);
        acc = __builtin_amdgcn_mfma_f32_16x16x32_bf16(a, bb, acc, 0, 0, 0);
      }
#pragma unroll
      for (int rr = 0; rr < 2; rr++) {
        TWl[s0][(T * 16 + col) * 10 + rb + 2 * rr]     = f2b(acc[2 * rr] + mtj[T]);
        TWl[s0][(T * 16 + col) * 10 + rb + 2 * rr + 1] = f2b(acc[2 * rr + 1] + mtj[T]);
      }
    }
#pragma unroll
    for (int s = 0; s < 2; s++) {
#pragma unroll
      for (int kk = 0; kk < 2; kk++) {
        int bi = (lane >> 4) + (kk << 2);
        int vloc = lane & 15;
        if (vloc < vlim) {
          u16 x = TWl[s][vloc * 30 + bi];
          u16 y = TWl[s][vloc * 30 + 10 + bi];
          u16 z = TWl[s][vloc * 30 + 20 + bi];
          u32x2 val;
          val.x = (u32)x | ((u32)y << 16);
          val.y = (u32)z;
          size_t idx = (((size_t)(bt * 2 + s) * NVERT + (vb + vloc)) * 8 + bi) * 2;
          __builtin_nontemporal_store(val, (u32x2*)(tex4 + idx));
        }
      }
    }
  }
}

// K3: face normals for 8 slabs (one per XCD). Split fxy/fz planes: per-XCD hot set =
// fq 3.40 MB + shpT 3.43 MB; fq planes stay in L2 for the paired k_final.
#define FN_CH2 2213   // ceil(NFACE/32)
__global__ __launch_bounds__(256) void k_fn(const float* __restrict__ shpT, const int* __restrict__ tri,
                                            u32* __restrict__ fxy, u16* __restrict__ fz, int lo) {
  int g = blockIdx.x;
  int xcd = g & 7, chunk = g >> 3;
  int bt8 = lo + xcd;
  int t = threadIdx.x;
  int bi = t & 7, foff = t >> 3;
  int f = chunk * 32 + foff;
  if (f >= NFACE) return;
  int i0 = tri[f * 3 + 0] - 1;
  int i1 = tri[f * 3 + 1] - 1;
  int i2 = tri[f * 3 + 2] - 1;
  const float* sl = shpT + (size_t)bt8 * (size_t)(NV3 * 8);
  int a0 = i0 * 24 + bi, a1 = i1 * 24 + bi, a2 = i2 * 24 + bi;
  float x1 = sl[a0], y1 = sl[a0 + 8], z1 = sl[a0 + 16];
  float x2 = sl[a1], y2 = sl[a1 + 8], z2 = sl[a1 + 16];
  float x3 = sl[a2], y3 = sl[a2 + 8], z3 = sl[a2 + 16];
  float e1x = x1 - x2, e1y = y1 - y2, e1z = z1 - z2;
  float e2x = x2 - x3, e2y = y2 - y3, e2z = z2 - z3;
  u16 hx = h2b(e1y * e2z - e1z * e2y);
  u16 hy = h2b(e1z * e2x - e1x * e2z);
  u16 hz = h2b(e1x * e2y - e1y * e2x);
  size_t o = (size_t)bt8 * (size_t)(NFACE * 8) + (size_t)f * 8 + bi;
  fxy[o] = (u32)hx | ((u32)hy << 16);
  fz[o] = hz;
}

// K4: face_color for 8 slabs (paired right after their k_fn): vn gather (L2-hot planes),
// rotate-normal + SH lighting; out via LDS transpose tile.
#define FI_CH2 1116   // ceil(NVERT/32)
__global__ __launch_bounds__(256) void k_final(const u32* __restrict__ tex4, const u32* __restrict__ fxy,
                                               const u16* __restrict__ fz, const int* __restrict__ pbuf,
                                               const float* __restrict__ mpad, const float* __restrict__ G,
                                               float* __restrict__ out, int lo) {
  __shared__ float scol[8][100];   // [bi][voff*3+c], pad 96->100
  int g = blockIdx.x;
  int xcd = g & 7, chunk = g >> 3;
  int bt8 = lo + xcd;
  int t = threadIdx.x;
  int bi = t & 7, voff = t >> 3;
  int v0 = chunk * 32;
  int v = v0 + voff;
  int vc = v < NVERT ? v : NVERT - 1;
  bool valid = v < NVERT;
  int b = bt8 * 8 + bi;
  i4 p0 = *(const i4*)(pbuf + (size_t)vc * 8);
  i4 p1 = *(const i4*)(pbuf + (size_t)vc * 8 + 4);
  int idx[8] = {p0.x, p0.y, p0.z, p0.w, p1.x, p1.y, p1.z, p1.w};
  const u32* fx = fxy + (size_t)bt8 * (size_t)(NFACE * 8);
  const u16* fzb = fz + (size_t)bt8 * (size_t)(NFACE * 8);
  float vx = 0.f, vy = 0.f, vz = 0.f;
#pragma unroll
  for (int i = 0; i < 8; i++) {
    int id = idx[i] - 1;               // in [0, NFACE]; NFACE == zero contribution
    if (id < NFACE) {
      u32 q = fx[(size_t)id * 8 + bi];
      u16 qz = fzb[(size_t)id * 8 + bi];
      vx += hb2f((u16)q); vy += hb2f((u16)(q >> 16)); vz += hb2f(qz);
    }
  }
  float n2 = vx * vx + vy * vy + vz * vz;
  float inv = rsqrtf(fmaxf(n2, 1e-30f));
  vx *= inv; vy *= inv; vz *= inv;
  const float* mp = mpad + b * 12;
  f4 m0 = *(const f4*)mp;
  f4 m1 = *(const f4*)(mp + 4);
  float m8 = mp[8];
  float nx = vx * m0.x + vy * m0.y + vz * m0.z;
  float ny = vx * m0.w + vy * m1.x + vz * m1.y;
  float nz = vx * m1.z + vy * m1.w + vz * m8;
  // SH lighting
  const float kc1 = 1.7724539f;             // a1*c1 = sqrt(pi)
  const float kc2 = 2.4270324f;             // a2*c2
  const float kd0 = 0.28867513f;            // 0.5/sqrt(3)
  float Y[9];
  Y[0] = 0.8862269f;                        // a0*c0
  Y[1] = -kc1 * ny;
  Y[2] = kc1 * nz;
  Y[3] = -kc1 * nx;
  Y[4] = kc2 * nx * ny;
  Y[5] = -kc2 * ny * nz;
  Y[6] = kc2 * kd0 * (3.f * nz * nz - 1.f);
  Y[7] = -kc2 * nx * nz;
  Y[8] = kc2 * 0.5f * (nx * nx - ny * ny);
  const float* gg = G + b * 27;
  float gv[28];
#pragma unroll
  for (int q = 0; q < 7; q++) {
    f4 g4 = ld4u(gg + q * 4);
    gv[q * 4] = g4.x; gv[q * 4 + 1] = g4.y; gv[q * 4 + 2] = g4.z; gv[q * 4 + 3] = g4.w;
  }
  if (valid) {
    u32x2 tv = __builtin_nontemporal_load(
        (const u32x2*)(tex4 + ((size_t)bt8 * NVERT + vc) * 16 + bi * 2));
    float tc[3] = { b2f((u16)tv.x), b2f((u16)(tv.x >> 16)), b2f((u16)tv.y) };
#pragma unroll
    for (int d = 0; d < 3; d++) {
      float L = 0.f;
#pragma unroll
      for (int cc = 0; cc < 9; cc++) L += Y[cc] * gv[cc * 3 + d];
      scol[bi][voff * 3 + d] = tc[d] * L;
    }
  }
  __syncthreads();
  int nvv = NVERT - v0;
  int lim = (nvv < 32 ? nvv : 32) * 3;
  size_t base = (size_t)(bt8 * 8) * NV3 + (size_t)v0 * 3;
#pragma unroll
  for (int it = 0; it < 3; it++) {
    int l = it * 256 + t;                  // 0..767
    int b2 = l / 96, e = l - b2 * 96;
    if (e < lim) {
      size_t o = base + (size_t)b2 * NV3 + e;
      __builtin_nontemporal_store(scol[b2][e], out + o);
    }
  }
}

// K5: landmarks — recompute shape_t at 68 kp verts from shpT, project (f32 out).
__global__ __launch_bounds__(128) void k_lms(const float* __restrict__ shpT, const int* __restrict__ kp,
                                             const float* __restrict__ mpad, float* __restrict__ out) {
  int t = threadIdx.x;
  int b = blockIdx.x;
  if (t >= 68) return;
  int v = kp[t];
  const float* sl = shpT + (size_t)(b >> 3) * (size_t)(NV3 * 8) + (size_t)v * 24 + (b & 7);
  float sx = sl[0], sy = sl[8], sz = sl[16];
  const float* mp = mpad + b * 12;
  f4 m0 = *(const f4*)mp;
  f4 m1 = *(const f4*)(mp + 4);
  f4 m2 = *(const f4*)(mp + 8);
  float ox = sx * m0.x + sy * m0.y + sz * m0.z + m2.y;
  float oy = sx * m0.w + sy * m1.x + sz * m1.y + m2.z;
  float oz = sx * m1.z + sy * m1.w + sz * m2.x + m2.w;
  float w = 10.f - oz;                      // pts@[1,1,-1] + [0,0,10]
  float invw = 1.0f / w;
  float lx = 1015.f * ox * invw + 128.f;    // FOCAL*x/w + half
  float ly = 1015.f * oy * invw + 128.f;
  size_t o = LMS_BASE + ((size_t)b * 68 + t) * 2;
  out[o + 0] = lx;
  out[o + 1] = 256.f - ly;                  // IMG - y
}

extern "C" void kernel_launch(void* const* d_in, const int* in_sizes, int n_in,
                              void* d_out, int out_size, void* d_ws, size_t ws_size,
                              hipStream_t stream) {
  const float* coeff     = (const float*)d_in[0];
  const float* meanshape = (const float*)d_in[1];
  const float* idB       = (const float*)d_in[2];
  const float* exB       = (const float*)d_in[3];
  const float* meantex   = (const float*)d_in[4];
  const float* txB       = (const float*)d_in[5];
  const int* tri         = (const int*)d_in[6];
  const int* pbuf        = (const int*)d_in[7];
  const int* kp          = (const int*)d_in[8];
  float* out = (float*)d_out;
  char* ws = (char*)d_ws;
  float* shpT = (float*)(ws + SHAPE_OFF);
  u32* tex4   = (u32*)(ws + TEX4_OFF);
  u32* fxy    = (u32*)(ws + FXY_OFF);
  u16* fzp    = (u16*)(ws + FZ_OFF);
  u16* cpack  = (u16*)(ws + CPACK_OFF);
  float* mpad = (float*)(ws + MPAD_OFF);
  float* G    = (float*)(ws + GG_OFF);
  float* mean = (float*)(ws + MEAN_OFF);
  float* part = (float*)(ws + PART_OFF);

  k_mean<<<64, 256, 0, stream>>>(meanshape, part);
  k_params<<<1, 128, 0, stream>>>(coeff, cpack, mpad, G, part, mean);
  k_gemmS<<<2 * SBLK, 256, 0, stream>>>(idB, exB, meanshape, cpack, mean, mpad, shpT, out);
  k_gemmT<<<2 * SBLK, 256, 0, stream>>>(txB, meantex, cpack, tex4);
  for (int lo = 0; lo < 16; lo += 8) {
    k_fn<<<8 * FN_CH2, 256, 0, stream>>>(shpT, tri, fxy, fzp, lo);
    k_final<<<8 * FI_CH2, 256, 0, stream>>>(tex4, fxy, fzp, pbuf, mpad, G, out, lo);
  }
  k_lms<<<128, 128, 0, stream>>>(shpT, kp, mpad, out);
}

// Round 8
// 439.400 us; speedup vs baseline: 1.1712x; 1.1712x over previous
//
#include <hip/hip_runtime.h>

typedef unsigned short u16;
typedef unsigned int u32;
typedef __attribute__((ext_vector_type(8))) short bfrag;     // 8 bf16 (4 VGPRs) MFMA A/B
typedef __attribute__((ext_vector_type(4))) float ffrag;     // 4 f32 MFMA C/D
typedef __attribute__((ext_vector_type(4))) float f4;
typedef __attribute__((ext_vector_type(2))) float f2;        // clang vector: ok for nontemporal builtins
typedef __attribute__((ext_vector_type(2))) u32 u32x2;
typedef __attribute__((ext_vector_type(4))) int i4;

#define NVERT 35709
#define NFACE 70789
#define NV3   107127
#define NB    128

// ---- workspace byte layout ----
// Batch-minor: slab = b>>3 (16 slabs), bi = b&7 innermost.
#define SHAPE_OFF 0ull            // f32 shpT[slab][j][bi]        (54,849,024 B)  j = v*3+c
#define TEX4_OFF  54849024ull     // u16 tex4[slab][v][bi][4]     (36,566,016 B)  (x,y,z,pad) bf16 bits
#define FXY_OFF   91415040ull     // u32 fxy[slab][f][bi]         (36,243,968 B)  fn (x|y<<16) f16 bits
#define FZ_OFF    127659008ull    // u16 fz [slab][f][bi]         (18,121,984 B)  fn z f16 bits
#define CPACK_OFF 145780992ull    // u16 bf16, NB*256 padded coeffs [id80|0*16|ex64|tex80|0*16]
#define MPAD_OFF  145846528ull    // f32 [128][12]: M[0..8], T[9..11]
#define GG_OFF    145852672ull    // f32 [128][27]: G[cc*3+d]
#define MEAN_OFF  145866496ull    // f32, 3 (+1 pad)
#define PART_OFF  145866512ull    // f32, 64*3 partial sums for mean

// ---- output element offsets (f32 out) ----
#define LMS_BASE  13712256ull     // after face_color (B*NV*3)
#define ST_BASE   13729664ull     // after lms (B*68*2)

__device__ __forceinline__ float b2f(u16 s) {
  union { unsigned u; float f; } v; v.u = ((unsigned)s) << 16; return v.f;
}
__device__ __forceinline__ u16 f2b(float x) {  // f32 -> bf16 RNE
  union { float f; unsigned u; } v; v.f = x;
  unsigned r = v.u + 0x7FFFu + ((v.u >> 16) & 1u);
  return (u16)(r >> 16);
}
__device__ __forceinline__ u16 h2b(float x) {  // f32 -> f16 bits
  union { _Float16 h; u16 u; } v; v.h = (_Float16)x; return v.u;
}
__device__ __forceinline__ float hb2f(u16 u) { // f16 bits -> f32
  union { _Float16 h; u16 u2; } v; v.u2 = u; return (float)v.h;
}
__device__ __forceinline__ f4 ld4u(const float* p) {  // 16 B load, 4 B aligned
  f4 r; __builtin_memcpy(&r, p, 16); return r;
}
__device__ __forceinline__ bfrag cvt8c(const float* p) {  // 8 f32 (cached) -> 8 bf16
  f4 a = *(const f4*)p;
  f4 b = *(const f4*)(p + 4);
  bfrag r;
  r[0] = (short)f2b(a.x); r[1] = (short)f2b(a.y); r[2] = (short)f2b(a.z); r[3] = (short)f2b(a.w);
  r[4] = (short)f2b(b.x); r[5] = (short)f2b(b.y); r[6] = (short)f2b(b.z); r[7] = (short)f2b(b.w);
  return r;
}

// K0: partial sums of meanshape over vertices (64 blocks x 3 comps)
__global__ __launch_bounds__(256) void k_mean(const float* __restrict__ ms, float* __restrict__ part) {
  __shared__ float s[3];
  if (threadIdx.x < 3) s[threadIdx.x] = 0.f;
  __syncthreads();
  float a0 = 0.f, a1 = 0.f, a2 = 0.f;
  for (int v = blockIdx.x * 256 + threadIdx.x; v < NVERT; v += 64 * 256) {
    a0 += ms[v * 3 + 0];
    a1 += ms[v * 3 + 1];
    a2 += ms[v * 3 + 2];
  }
  atomicAdd(&s[0], a0); atomicAdd(&s[1], a1); atomicAdd(&s[2], a2);
  __syncthreads();
  if (threadIdx.x < 3) part[blockIdx.x * 3 + threadIdx.x] = s[threadIdx.x];
}

// K1: finalize mean; per-batch params: cpack bf16 coeffs, mpad[b][12] = M[9]+T[3], G[b][27]
__global__ __launch_bounds__(128) void k_params(const float* __restrict__ coeff, u16* __restrict__ cpack,
                                                float* __restrict__ mpad, float* __restrict__ G,
                                                const float* __restrict__ part, float* __restrict__ mean) {
  int b = threadIdx.x;
  if (b < 3) {
    float s = 0.f;
    for (int i = 0; i < 64; i++) s += part[i * 3 + b];
    mean[b] = s * (1.0f / (float)NVERT);
  }
  const float* c = coeff + b * 257;
  u16* cp = cpack + b * 256;
  for (int k = 0; k < 80; k++) cp[k] = f2b(c[k]);            // id
  for (int k = 80; k < 96; k++) cp[k] = 0;                   // pad
  for (int k = 0; k < 64; k++) cp[96 + k] = f2b(c[80 + k]);  // ex
  for (int k = 0; k < 80; k++) cp[160 + k] = f2b(c[144 + k]);// tex
  for (int k = 240; k < 256; k++) cp[k] = 0;                 // pad
  float ax = c[224], ay = c[225], az = c[226];
  float sx = sinf(ax), cx = cosf(ax);
  float sy = sinf(ay), cy = cosf(ay);
  float sz = sinf(az), cz = cosf(az);
  float* mp = mpad + b * 12;
  mp[0] = cz * cy;  mp[1] = cz * sy * sx - sz * cx;  mp[2] = sz * sx + cz * sy * cx;
  mp[3] = sz * cy;  mp[4] = cz * cx + sz * sy * sx;  mp[5] = sz * sy * cx - cz * sx;
  mp[6] = -sy;      mp[7] = cy * sx;                 mp[8] = cy * cx;
  mp[9] = c[254]; mp[10] = c[255]; mp[11] = c[256];
  float* g = G + b * 27;
  for (int cc = 0; cc < 9; cc++)
    for (int d = 0; d < 3; d++)
      g[cc * 3 + d] = c[227 + d * 9 + cc] + (cc == 0 ? 0.8f : 0.0f);
}

// K2: FUSED shape+tex GEMM (round-6 bodies, one-time B-frag loads — the 4x-reload
// experiment of round 7 thrashed L3 and went to HBM; reverted). Parity role-split:
// even blocks run the shape path, odd blocks the tex path — both co-resident from t=0
// so T's latency hides under S's writes and vice versa. Shared 15.4 KB LDS window.
#define SBLK 558   // ceil(NV3 / 192)
__global__ __launch_bounds__(256) void k_gemm2(const float* __restrict__ idB, const float* __restrict__ exB,
                                               const float* __restrict__ txB, const float* __restrict__ ms,
                                               const float* __restrict__ mt, const u16* __restrict__ cpack,
                                               const float* __restrict__ meanc, const float* __restrict__ mpad,
                                               float* __restrict__ shp, u32* __restrict__ tex4,
                                               float* __restrict__ out) {
  __shared__ float SW[4][2][480];   // [wave][window s][48 j * 10]; T path reinterprets as u16
  int half = blockIdx.x >> 1;
  int isS = !(blockIdx.x & 1);
  int jblk = half % SBLK, split = half / SBLK;
  int wave = threadIdx.x >> 6, lane = threadIdx.x & 63;
  int col = lane & 15, quad = lane >> 4;
  int jb = (jblk * 4 + wave) * 48;
  bfrag z8 = {0, 0, 0, 0, 0, 0, 0, 0};
  int s0 = quad >> 1;
  int rb = (quad & 1) << 2;
  int vb = jb / 3;
  int ilim = NV3 - jb; ilim = (ilim > 48 ? 48 : ilim) * 8;
  int vlim = NVERT - vb; vlim = vlim > 16 ? 16 : vlim;

  if (isS) {
    // ---------------- shape path (round-6 k_gemmS) ----------------
    bfrag bid[3][3], bex[3][2];
    float msub[3];
#pragma unroll
    for (int T = 0; T < 3; T++) {
      int j = jb + T * 16 + col;
      int jc = j < NV3 ? j : NV3 - 1;
      const float* rowI = idB + (size_t)jc * 80;
      const float* rowE = exB + (size_t)jc * 64;
#pragma unroll
      for (int f = 0; f < 3; f++) {
        int k = f * 32 + quad * 8;
        bool ok = (k < 80);
        int ks = ok ? k : 0;
        bfrag vi = cvt8c(rowI + ks);
        bid[T][f] = ok ? vi : z8;
      }
#pragma unroll
      for (int f = 0; f < 2; f++) bex[T][f] = cvt8c(rowE + f * 32 + quad * 8);
      msub[T] = ms[jc] - meanc[jc % 3];
    }
    float (*SWl)[480] = SW[wave];

    for (int bt = split * 4; bt < split * 4 + 4; bt++) {
      const u16* cp = cpack + (size_t)(bt * 16 + col) * 256;
#pragma unroll
      for (int T = 0; T < 3; T++) {
        ffrag acc = {0.f, 0.f, 0.f, 0.f};
#pragma unroll
        for (int f = 0; f < 3; f++) {
          bfrag a = *(const bfrag*)(cp + f * 32 + quad * 8);
          acc = __builtin_amdgcn_mfma_f32_16x16x32_bf16(a, bid[T][f], acc, 0, 0, 0);
        }
#pragma unroll
        for (int f = 0; f < 2; f++) {
          bfrag a = *(const bfrag*)(cp + 96 + f * 32 + quad * 8);
          acc = __builtin_amdgcn_mfma_f32_16x16x32_bf16(a, bex[T][f], acc, 0, 0, 0);
        }
#pragma unroll
        for (int rr = 0; rr < 2; rr++) {
          f2 v2;
          v2.x = acc[2 * rr] + msub[T];
          v2.y = acc[2 * rr + 1] + msub[T];
          *(f2*)&SWl[s0][(T * 16 + col) * 10 + rb + 2 * rr] = v2;
        }
      }
      // raw shpT copy (coalesced; padded LDS -> addr = j*10 + bi)
#pragma unroll
      for (int s = 0; s < 2; s++) {
        size_t sb = (size_t)(bt * 2 + s) * (size_t)(NV3 * 8) + (size_t)jb * 8;
#pragma unroll
        for (int it = 0; it < 3; it++) {
          int i = it * 128 + lane * 2;
          if (i < ilim) {
            f2 vv = *(f2*)&SWl[s][(i >> 3) * 10 + (i & 7)];
            __builtin_nontemporal_store(vv, (f2*)(shp + sb + i));
          }
        }
      }
      // rotated shape_t -> out
#pragma unroll
      for (int s = 0; s < 2; s++) {
#pragma unroll
        for (int kk = 0; kk < 2; kk++) {
          int bi = (lane >> 4) + (kk << 2);
          int vloc = lane & 15;
          int b = bt * 16 + s * 8 + bi;
          float x = SWl[s][vloc * 30 + bi];
          float y = SWl[s][vloc * 30 + 10 + bi];
          float z = SWl[s][vloc * 30 + 20 + bi];
          const float* mp = mpad + b * 12;
          f4 m0 = *(const f4*)mp;
          f4 m1 = *(const f4*)(mp + 4);
          f4 m2 = *(const f4*)(mp + 8);
          if (vloc < vlim) {
            float ox = x * m0.x + y * m0.y + z * m0.z + m2.y;
            float oy = x * m0.w + y * m1.x + z * m1.y + m2.z;
            float oz = x * m1.z + y * m1.w + z * m2.x + m2.w;
            size_t o = ST_BASE + (size_t)b * NV3 + (size_t)(vb + vloc) * 3;
            __builtin_nontemporal_store(ox, out + o);
            __builtin_nontemporal_store(oy, out + o + 1);
            __builtin_nontemporal_store(oz, out + o + 2);
          }
        }
      }
    }
  } else {
    // ---------------- tex path (round-6 k_gemmT) ----------------
    bfrag btx[3][3];
    float mtj[3];
#pragma unroll
    for (int T = 0; T < 3; T++) {
      int j = jb + T * 16 + col;
      int jc = j < NV3 ? j : NV3 - 1;
      const float* rowT = txB + (size_t)jc * 80;
#pragma unroll
      for (int f = 0; f < 3; f++) {
        int k = f * 32 + quad * 8;
        bool ok = (k < 80);
        int ks = ok ? k : 0;
        bfrag vt = cvt8c(rowT + ks);
        btx[T][f] = ok ? vt : z8;
      }
      mtj[T] = mt[jc];
    }
    u16 (*TWl)[480] = (u16 (*)[480])SW[wave];   // u16 view fits in the float window

    for (int bt = split * 4; bt < split * 4 + 4; bt++) {
      const u16* cp = cpack + (size_t)(bt * 16 + col) * 256;
#pragma unroll
      for (int T = 0; T < 3; T++) {
        ffrag acc = {0.f, 0.f, 0.f, 0.f};
#pragma unroll
        for (int f = 0; f < 3; f++) {
          bfrag a = *(const bfrag*)(cp + 160 + f * 32 + quad * 8);
          acc = __builtin_amdgcn_mfma_f32_16x16x32_bf16(a, btx[T][f], acc, 0, 0, 0);
        }
#pragma unroll
        for (int rr = 0; rr < 2; rr++) {
          TWl[s0][(T * 16 + col) * 10 + rb + 2 * rr]     = f2b(acc[2 * rr] + mtj[T]);
          TWl[s0][(T * 16 + col) * 10 + rb + 2 * rr + 1] = f2b(acc[2 * rr + 1] + mtj[T]);
        }
      }
#pragma unroll
      for (int s = 0; s < 2; s++) {
#pragma unroll
        for (int kk = 0; kk < 2; kk++) {
          int bi = (lane >> 4) + (kk << 2);
          int vloc = lane & 15;
          if (vloc < vlim) {
            u16 x = TWl[s][vloc * 30 + bi];
            u16 y = TWl[s][vloc * 30 + 10 + bi];
            u16 z = TWl[s][vloc * 30 + 20 + bi];
            u32x2 val;
            val.x = (u32)x | ((u32)y << 16);
            val.y = (u32)z;
            size_t idx = (((size_t)(bt * 2 + s) * NVERT + (vb + vloc)) * 8 + bi) * 2;
            __builtin_nontemporal_store(val, (u32x2*)(tex4 + idx));
          }
        }
      }
    }
  }
}

// K3: face normals for 8 slabs (one per XCD). Split fxy/fz planes: per-XCD hot set =
// fq 3.40 MB + shpT 3.43 MB; fq planes stay in L2 for the paired k_final.
#define FN_CH2 2213   // ceil(NFACE/32)
__global__ __launch_bounds__(256) void k_fn(const float* __restrict__ shpT, const int* __restrict__ tri,
                                            u32* __restrict__ fxy, u16* __restrict__ fz, int lo) {
  int g = blockIdx.x;
  int xcd = g & 7, chunk = g >> 3;
  int bt8 = lo + xcd;
  int t = threadIdx.x;
  int bi = t & 7, foff = t >> 3;
  int f = chunk * 32 + foff;
  if (f >= NFACE) return;
  int i0 = tri[f * 3 + 0] - 1;
  int i1 = tri[f * 3 + 1] - 1;
  int i2 = tri[f * 3 + 2] - 1;
  const float* sl = shpT + (size_t)bt8 * (size_t)(NV3 * 8);
  int a0 = i0 * 24 + bi, a1 = i1 * 24 + bi, a2 = i2 * 24 + bi;
  float x1 = sl[a0], y1 = sl[a0 + 8], z1 = sl[a0 + 16];
  float x2 = sl[a1], y2 = sl[a1 + 8], z2 = sl[a1 + 16];
  float x3 = sl[a2], y3 = sl[a2 + 8], z3 = sl[a2 + 16];
  float e1x = x1 - x2, e1y = y1 - y2, e1z = z1 - z2;
  float e2x = x2 - x3, e2y = y2 - y3, e2z = z2 - z3;
  u16 hx = h2b(e1y * e2z - e1z * e2y);
  u16 hy = h2b(e1z * e2x - e1x * e2z);
  u16 hz = h2b(e1x * e2y - e1y * e2x);
  size_t o = (size_t)bt8 * (size_t)(NFACE * 8) + (size_t)f * 8 + bi;
  fxy[o] = (u32)hx | ((u32)hy << 16);
  fz[o] = hz;
}

// K4: face_color for 8 slabs (paired right after their k_fn): vn gather (L2-hot planes),
// rotate-normal + SH lighting; out via LDS transpose tile.
#define FI_CH2 1116   // ceil(NVERT/32)
__global__ __launch_bounds__(256) void k_final(const u32* __restrict__ tex4, const u32* __restrict__ fxy,
                                               const u16* __restrict__ fz, const int* __restrict__ pbuf,
                                               const float* __restrict__ mpad, const float* __restrict__ G,
                                               float* __restrict__ out, int lo) {
  __shared__ float scol[8][100];   // [bi][voff*3+c], pad 96->100
  int g = blockIdx.x;
  int xcd = g & 7, chunk = g >> 3;
  int bt8 = lo + xcd;
  int t = threadIdx.x;
  int bi = t & 7, voff = t >> 3;
  int v0 = chunk * 32;
  int v = v0 + voff;
  int vc = v < NVERT ? v : NVERT - 1;
  bool valid = v < NVERT;
  int b = bt8 * 8 + bi;
  i4 p0 = *(const i4*)(pbuf + (size_t)vc * 8);
  i4 p1 = *(const i4*)(pbuf + (size_t)vc * 8 + 4);
  int idx[8] = {p0.x, p0.y, p0.z, p0.w, p1.x, p1.y, p1.z, p1.w};
  const u32* fx = fxy + (size_t)bt8 * (size_t)(NFACE * 8);
  const u16* fzb = fz + (size_t)bt8 * (size_t)(NFACE * 8);
  float vx = 0.f, vy = 0.f, vz = 0.f;
#pragma unroll
  for (int i = 0; i < 8; i++) {
    int id = idx[i] - 1;               // in [0, NFACE]; NFACE == zero contribution
    if (id < NFACE) {
      u32 q = fx[(size_t)id * 8 + bi];
      u16 qz = fzb[(size_t)id * 8 + bi];
      vx += hb2f((u16)q); vy += hb2f((u16)(q >> 16)); vz += hb2f(qz);
    }
  }
  float n2 = vx * vx + vy * vy + vz * vz;
  float inv = rsqrtf(fmaxf(n2, 1e-30f));
  vx *= inv; vy *= inv; vz *= inv;
  const float* mp = mpad + b * 12;
  f4 m0 = *(const f4*)mp;
  f4 m1 = *(const f4*)(mp + 4);
  float m8 = mp[8];
  float nx = vx * m0.x + vy * m0.y + vz * m0.z;
  float ny = vx * m0.w + vy * m1.x + vz * m1.y;
  float nz = vx * m1.z + vy * m1.w + vz * m8;
  // SH lighting
  const float kc1 = 1.7724539f;             // a1*c1 = sqrt(pi)
  const float kc2 = 2.4270324f;             // a2*c2
  const float kd0 = 0.28867513f;            // 0.5/sqrt(3)
  float Y[9];
  Y[0] = 0.8862269f;                        // a0*c0
  Y[1] = -kc1 * ny;
  Y[2] = kc1 * nz;
  Y[3] = -kc1 * nx;
  Y[4] = kc2 * nx * ny;
  Y[5] = -kc2 * ny * nz;
  Y[6] = kc2 * kd0 * (3.f * nz * nz - 1.f);
  Y[7] = -kc2 * nx * nz;
  Y[8] = kc2 * 0.5f * (nx * nx - ny * ny);
  const float* gg = G + b * 27;
  float gv[28];
#pragma unroll
  for (int q = 0; q < 7; q++) {
    f4 g4 = ld4u(gg + q * 4);
    gv[q * 4] = g4.x; gv[q * 4 + 1] = g4.y; gv[q * 4 + 2] = g4.z; gv[q * 4 + 3] = g4.w;
  }
  if (valid) {
    u32x2 tv = __builtin_nontemporal_load(
        (const u32x2*)(tex4 + ((size_t)bt8 * NVERT + vc) * 16 + bi * 2));
    float tc[3] = { b2f((u16)tv.x), b2f((u16)(tv.x >> 16)), b2f((u16)tv.y) };
#pragma unroll
    for (int d = 0; d < 3; d++) {
      float L = 0.f;
#pragma unroll
      for (int cc = 0; cc < 9; cc++) L += Y[cc] * gv[cc * 3 + d];
      scol[bi][voff * 3 + d] = tc[d] * L;
    }
  }
  __syncthreads();
  int nvv = NVERT - v0;
  int lim = (nvv < 32 ? nvv : 32) * 3;
  size_t base = (size_t)(bt8 * 8) * NV3 + (size_t)v0 * 3;
#pragma unroll
  for (int it = 0; it < 3; it++) {
    int l = it * 256 + t;                  // 0..767
    int b2 = l / 96, e = l - b2 * 96;
    if (e < lim) {
      size_t o = base + (size_t)b2 * NV3 + e;
      __builtin_nontemporal_store(scol[b2][e], out + o);
    }
  }
}

// K5: landmarks — recompute shape_t at 68 kp verts from shpT, project (f32 out).
__global__ __launch_bounds__(128) void k_lms(const float* __restrict__ shpT, const int* __restrict__ kp,
                                             const float* __restrict__ mpad, float* __restrict__ out) {
  int t = threadIdx.x;
  int b = blockIdx.x;
  if (t >= 68) return;
  int v = kp[t];
  const float* sl = shpT + (size_t)(b >> 3) * (size_t)(NV3 * 8) + (size_t)v * 24 + (b & 7);
  float sx = sl[0], sy = sl[8], sz = sl[16];
  const float* mp = mpad + b * 12;
  f4 m0 = *(const f4*)mp;
  f4 m1 = *(const f4*)(mp + 4);
  f4 m2 = *(const f4*)(mp + 8);
  float ox = sx * m0.x + sy * m0.y + sz * m0.z + m2.y;
  float oy = sx * m0.w + sy * m1.x + sz * m1.y + m2.z;
  float oz = sx * m1.z + sy * m1.w + sz * m2.x + m2.w;
  float w = 10.f - oz;                      // pts@[1,1,-1] + [0,0,10]
  float invw = 1.0f / w;
  float lx = 1015.f * ox * invw + 128.f;    // FOCAL*x/w + half
  float ly = 1015.f * oy * invw + 128.f;
  size_t o = LMS_BASE + ((size_t)b * 68 + t) * 2;
  out[o + 0] = lx;
  out[o + 1] = 256.f - ly;                  // IMG - y
}

extern "C" void kernel_launch(void* const* d_in, const int* in_sizes, int n_in,
                              void* d_out, int out_size, void* d_ws, size_t ws_size,
                              hipStream_t stream) {
  const float* coeff     = (const float*)d_in[0];
  const float* meanshape = (const float*)d_in[1];
  const float* idB       = (const float*)d_in[2];
  const float* exB       = (const float*)d_in[3];
  const float* meantex   = (const float*)d_in[4];
  const float* txB       = (const float*)d_in[5];
  const int* tri         = (const int*)d_in[6];
  const int* pbuf        = (const int*)d_in[7];
  const int* kp          = (const int*)d_in[8];
  float* out = (float*)d_out;
  char* ws = (char*)d_ws;
  float* shpT = (float*)(ws + SHAPE_OFF);
  u32* tex4   = (u32*)(ws + TEX4_OFF);
  u32* fxy    = (u32*)(ws + FXY_OFF);
  u16* fzp    = (u16*)(ws + FZ_OFF);
  u16* cpack  = (u16*)(ws + CPACK_OFF);
  float* mpad = (float*)(ws + MPAD_OFF);
  float* G    = (float*)(ws + GG_OFF);
  float* mean = (float*)(ws + MEAN_OFF);
  float* part = (float*)(ws + PART_OFF);

  k_mean<<<64, 256, 0, stream>>>(meanshape, part);
  k_params<<<1, 128, 0, stream>>>(coeff, cpack, mpad, G, part, mean);
  k_gemm2<<<4 * SBLK, 256, 0, stream>>>(idB, exB, txB, meanshape, meantex, cpack, mean, mpad,
                                        shpT, tex4, out);
  for (int lo = 0; lo < 16; lo += 8) {
    k_fn<<<8 * FN_CH2, 256, 0, stream>>>(shpT, tri, fxy, fzp, lo);
    k_final<<<8 * FI_CH2, 256, 0, stream>>>(tex4, fxy, fzp, pbuf, mpad, G, out, lo);
  }
  k_lms<<<128, 128, 0, stream>>>(shpT, kp, mpad, out);
}

// Round 9
// 408.860 us; speedup vs baseline: 1.2587x; 1.0747x over previous
//
#include <hip/hip_runtime.h>

typedef unsigned short u16;
typedef unsigned int u32;
typedef __attribute__((ext_vector_type(8))) short bfrag;     // 8 bf16 (4 VGPRs) MFMA A/B
typedef __attribute__((ext_vector_type(4))) float ffrag;     // 4 f32 MFMA C/D
typedef __attribute__((ext_vector_type(4))) float f4;
typedef __attribute__((ext_vector_type(2))) float f2;        // clang vector: ok for nontemporal builtins
typedef __attribute__((ext_vector_type(4))) int i4;
typedef __attribute__((ext_vector_type(4))) _Float16 h4;     // fn record: xyz + pad, 8 B
typedef __attribute__((ext_vector_type(8))) _Float16 h8;     // 2 fn records (bi-pair), 16 B

#define NVERT 35709
#define NFACE 70789
#define NV3   107127
#define NB    128

// ---- workspace byte layout (r4 envelope, end 154,847,760 B) ----
// Batch-minor: slab = b>>3 (16 slabs), bi = b&7 innermost.
#define SHAPE_OFF 0ull            // f32 shpT[slab][j][bi]   (54,849,024 B)  j = v*3+c
#define TEX_OFF   54849024ull     // u16 texT[slab][j][bi]   (27,424,512 B)  bf16 bits
#define FQ_OFF    82273536ull     // h4 fq[slab][f][bi]      (72,487,936 B)  fused f16x4 fn record
#define CPACK_OFF 154761472ull    // u16 bf16, NB*256 padded coeffs [id80|0*16|ex64|tex80|0*16]
#define MPAD_OFF  154827008ull    // f32 [128][12]: M[0..8], T[9..11]
#define GG_OFF    154833152ull    // f32 [128][27]: G[cc*3+d]
#define MEAN_OFF  154846976ull    // f32, 3 (+1 pad)
#define PART_OFF  154846992ull    // f32, 64*3 partial sums for mean (end 154,847,760)

// ---- output element offsets (f32 out) ----
#define LMS_BASE  13712256ull     // after face_color (B*NV*3)
#define ST_BASE   13729664ull     // after lms (B*68*2)

__device__ __forceinline__ float b2f(u16 s) {
  union { unsigned u; float f; } v; v.u = ((unsigned)s) << 16; return v.f;
}
__device__ __forceinline__ u16 f2b(float x) {  // f32 -> bf16 RNE
  union { float f; unsigned u; } v; v.f = x;
  unsigned r = v.u + 0x7FFFu + ((v.u >> 16) & 1u);
  return (u16)(r >> 16);
}
__device__ __forceinline__ f4 ld4u(const float* p) {  // 16 B load, 4 B aligned
  f4 r; __builtin_memcpy(&r, p, 16); return r;
}
__device__ __forceinline__ bfrag cvt8c(const float* p) {  // 8 f32 (cached) -> 8 bf16
  f4 a = *(const f4*)p;
  f4 b = *(const f4*)(p + 4);
  bfrag r;
  r[0] = (short)f2b(a.x); r[1] = (short)f2b(a.y); r[2] = (short)f2b(a.z); r[3] = (short)f2b(a.w);
  r[4] = (short)f2b(b.x); r[5] = (short)f2b(b.y); r[6] = (short)f2b(b.z); r[7] = (short)f2b(b.w);
  return r;
}

// K0: partial sums of meanshape over vertices (64 blocks x 3 comps)
__global__ __launch_bounds__(256) void k_mean(const float* __restrict__ ms, float* __restrict__ part) {
  __shared__ float s[3];
  if (threadIdx.x < 3) s[threadIdx.x] = 0.f;
  __syncthreads();
  float a0 = 0.f, a1 = 0.f, a2 = 0.f;
  for (int v = blockIdx.x * 256 + threadIdx.x; v < NVERT; v += 64 * 256) {
    a0 += ms[v * 3 + 0];
    a1 += ms[v * 3 + 1];
    a2 += ms[v * 3 + 2];
  }
  atomicAdd(&s[0], a0); atomicAdd(&s[1], a1); atomicAdd(&s[2], a2);
  __syncthreads();
  if (threadIdx.x < 3) part[blockIdx.x * 3 + threadIdx.x] = s[threadIdx.x];
}

// K1: finalize mean; per-batch params: cpack bf16 coeffs, mpad[b][12] = M[9]+T[3], G[b][27]
__global__ __launch_bounds__(128) void k_params(const float* __restrict__ coeff, u16* __restrict__ cpack,
                                                float* __restrict__ mpad, float* __restrict__ G,
                                                const float* __restrict__ part, float* __restrict__ mean) {
  int b = threadIdx.x;
  if (b < 3) {
    float s = 0.f;
    for (int i = 0; i < 64; i++) s += part[i * 3 + b];
    mean[b] = s * (1.0f / (float)NVERT);
  }
  const float* c = coeff + b * 257;
  u16* cp = cpack + b * 256;
  for (int k = 0; k < 80; k++) cp[k] = f2b(c[k]);            // id
  for (int k = 80; k < 96; k++) cp[k] = 0;                   // pad
  for (int k = 0; k < 64; k++) cp[96 + k] = f2b(c[80 + k]);  // ex
  for (int k = 0; k < 80; k++) cp[160 + k] = f2b(c[144 + k]);// tex
  for (int k = 240; k < 256; k++) cp[k] = 0;                 // pad
  float ax = c[224], ay = c[225], az = c[226];
  float sx = sinf(ax), cx = cosf(ax);
  float sy = sinf(ay), cy = cosf(ay);
  float sz = sinf(az), cz = cosf(az);
  float* mp = mpad + b * 12;
  mp[0] = cz * cy;  mp[1] = cz * sy * sx - sz * cx;  mp[2] = sz * sx + cz * sy * cx;
  mp[3] = sz * cy;  mp[4] = cz * cx + sz * sy * sx;  mp[5] = sz * sy * cx - cz * sx;
  mp[6] = -sy;      mp[7] = cy * sx;                 mp[8] = cy * cx;
  mp[9] = c[254]; mp[10] = c[255]; mp[11] = c[256];
  float* g = G + b * 27;
  for (int cc = 0; cc < 9; cc++)
    for (int d = 0; d < 3; d++)
      g[cc * 3 + d] = c[227 + d * 9 + cc] + (cc == 0 ? 0.8f : 0.0f);
}

// K2a: shape GEMM (round-6 verbatim — measured 67 us, FETCH 61 MB = one base read).
// Wave owns 48 j = 16 vertices; bt split across 2 block groups; stride-10 LDS padding.
#define SBLK 558   // ceil(NV3 / 192)
__global__ __launch_bounds__(256) void k_gemmS(const float* __restrict__ idB, const float* __restrict__ exB,
                                               const float* __restrict__ ms, const u16* __restrict__ cpack,
                                               const float* __restrict__ meanc, const float* __restrict__ mpad,
                                               float* __restrict__ shp, float* __restrict__ out) {
  __shared__ float SW[4][2][480];   // [wave][window s][48 j * 10]
  int jblk = blockIdx.x % SBLK, split = blockIdx.x / SBLK;
  int wave = threadIdx.x >> 6, lane = threadIdx.x & 63;
  int col = lane & 15, quad = lane >> 4;
  int jb = (jblk * 4 + wave) * 48;
  bfrag z8 = {0, 0, 0, 0, 0, 0, 0, 0};
  bfrag bid[3][3], bex[3][2];
  float msub[3];
#pragma unroll
  for (int T = 0; T < 3; T++) {
    int j = jb + T * 16 + col;
    int jc = j < NV3 ? j : NV3 - 1;
    const float* rowI = idB + (size_t)jc * 80;
    const float* rowE = exB + (size_t)jc * 64;
#pragma unroll
    for (int f = 0; f < 3; f++) {
      int k = f * 32 + quad * 8;
      bool ok = (k < 80);
      int ks = ok ? k : 0;
      bfrag vi = cvt8c(rowI + ks);
      bid[T][f] = ok ? vi : z8;
    }
#pragma unroll
    for (int f = 0; f < 2; f++) bex[T][f] = cvt8c(rowE + f * 32 + quad * 8);
    msub[T] = ms[jc] - meanc[jc % 3];
  }
  float (*SWl)[480] = SW[wave];
  int s0 = quad >> 1;
  int rb = (quad & 1) << 2;
  int vb = jb / 3;
  int ilim = NV3 - jb; ilim = (ilim > 48 ? 48 : ilim) * 8;
  int vlim = NVERT - vb; vlim = vlim > 16 ? 16 : vlim;

  for (int bt = split * 4; bt < split * 4 + 4; bt++) {
    const u16* cp = cpack + (size_t)(bt * 16 + col) * 256;
#pragma unroll
    for (int T = 0; T < 3; T++) {
      ffrag acc = {0.f, 0.f, 0.f, 0.f};
#pragma unroll
      for (int f = 0; f < 3; f++) {
        bfrag a = *(const bfrag*)(cp + f * 32 + quad * 8);
        acc = __builtin_amdgcn_mfma_f32_16x16x32_bf16(a, bid[T][f], acc, 0, 0, 0);
      }
#pragma unroll
      for (int f = 0; f < 2; f++) {
        bfrag a = *(const bfrag*)(cp + 96 + f * 32 + quad * 8);
        acc = __builtin_amdgcn_mfma_f32_16x16x32_bf16(a, bex[T][f], acc, 0, 0, 0);
      }
#pragma unroll
      for (int rr = 0; rr < 2; rr++) {
        f2 v2;
        v2.x = acc[2 * rr] + msub[T];
        v2.y = acc[2 * rr + 1] + msub[T];
        *(f2*)&SWl[s0][(T * 16 + col) * 10 + rb + 2 * rr] = v2;
      }
    }
    // raw shpT copy (coalesced; padded LDS -> addr = j*10 + bi)
#pragma unroll
    for (int s = 0; s < 2; s++) {
      size_t sb = (size_t)(bt * 2 + s) * (size_t)(NV3 * 8) + (size_t)jb * 8;
#pragma unroll
      for (int it = 0; it < 3; it++) {
        int i = it * 128 + lane * 2;
        if (i < ilim) {
          f2 vv = *(f2*)&SWl[s][(i >> 3) * 10 + (i & 7)];
          __builtin_nontemporal_store(vv, (f2*)(shp + sb + i));
        }
      }
    }
    // rotated shape_t -> out
#pragma unroll
    for (int s = 0; s < 2; s++) {
#pragma unroll
      for (int kk = 0; kk < 2; kk++) {
        int bi = (lane >> 4) + (kk << 2);
        int vloc = lane & 15;
        int b = bt * 16 + s * 8 + bi;
        float x = SWl[s][vloc * 30 + bi];
        float y = SWl[s][vloc * 30 + 10 + bi];
        float z = SWl[s][vloc * 30 + 20 + bi];
        const float* mp = mpad + b * 12;
        f4 m0 = *(const f4*)mp;
        f4 m1 = *(const f4*)(mp + 4);
        f4 m2 = *(const f4*)(mp + 8);
        if (vloc < vlim) {
          float ox = x * m0.x + y * m0.y + z * m0.z + m2.y;
          float oy = x * m0.w + y * m1.x + z * m1.y + m2.z;
          float oz = x * m1.z + y * m1.w + z * m2.x + m2.w;
          size_t o = ST_BASE + (size_t)b * NV3 + (size_t)(vb + vloc) * 3;
          __builtin_nontemporal_store(ox, out + o);
          __builtin_nontemporal_store(oy, out + o + 1);
          __builtin_nontemporal_store(oz, out + o + 2);
        }
      }
    }
  }
}

// K2b: tex GEMM (round-6 body) -> texT[slab][j][bi] u16 via raw coalesced copy.
__global__ __launch_bounds__(256) void k_gemmT(const float* __restrict__ txB, const float* __restrict__ mt,
                                               const u16* __restrict__ cpack, u16* __restrict__ texo) {
  __shared__ u16 TW[4][2][480];   // [wave][window s][48 j * 10]
  int jblk = blockIdx.x % SBLK, split = blockIdx.x / SBLK;
  int wave = threadIdx.x >> 6, lane = threadIdx.x & 63;
  int col = lane & 15, quad = lane >> 4;
  int jb = (jblk * 4 + wave) * 48;
  bfrag z8 = {0, 0, 0, 0, 0, 0, 0, 0};
  bfrag btx[3][3];
  float mtj[3];
#pragma unroll
  for (int T = 0; T < 3; T++) {
    int j = jb + T * 16 + col;
    int jc = j < NV3 ? j : NV3 - 1;
    const float* rowT = txB + (size_t)jc * 80;
#pragma unroll
    for (int f = 0; f < 3; f++) {
      int k = f * 32 + quad * 8;
      bool ok = (k < 80);
      int ks = ok ? k : 0;
      bfrag vt = cvt8c(rowT + ks);
      btx[T][f] = ok ? vt : z8;
    }
    mtj[T] = mt[jc];
  }
  u16 (*TWl)[480] = TW[wave];
  int s0 = quad >> 1;
  int rb = (quad & 1) << 2;
  int ilim = NV3 - jb; ilim = (ilim > 48 ? 48 : ilim) * 8;

  for (int bt = split * 4; bt < split * 4 + 4; bt++) {
    const u16* cp = cpack + (size_t)(bt * 16 + col) * 256;
#pragma unroll
    for (int T = 0; T < 3; T++) {
      ffrag acc = {0.f, 0.f, 0.f, 0.f};
#pragma unroll
      for (int f = 0; f < 3; f++) {
        bfrag a = *(const bfrag*)(cp + 160 + f * 32 + quad * 8);
        acc = __builtin_amdgcn_mfma_f32_16x16x32_bf16(a, btx[T][f], acc, 0, 0, 0);
      }
#pragma unroll
      for (int rr = 0; rr < 2; rr++) {
        TWl[s0][(T * 16 + col) * 10 + rb + 2 * rr]     = f2b(acc[2 * rr] + mtj[T]);
        TWl[s0][(T * 16 + col) * 10 + rb + 2 * rr + 1] = f2b(acc[2 * rr + 1] + mtj[T]);
      }
    }
    // raw texT copy (coalesced u32 pairs)
#pragma unroll
    for (int s = 0; s < 2; s++) {
      size_t sb = (size_t)(bt * 2 + s) * (size_t)(NV3 * 8) + (size_t)jb * 8;
#pragma unroll
      for (int it = 0; it < 3; it++) {
        int i = it * 128 + lane * 2;
        if (i < ilim) {
          int li = (i >> 3) * 10 + (i & 7);
          u32 val = (u32)TWl[s][li] | ((u32)TWl[s][li + 1] << 16);
          __builtin_nontemporal_store(val, (u32*)(texo + sb + i));
        }
      }
    }
  }
}

// K3: face normals, bi-PAIR threads: 9 f2 loads + 2 crosses + one 16 B store per thread
// (half the instructions per output of the 1-bi version). Fused f16x4 record so the
// consumer gathers one 16 B line per pair. 8 slabs/launch (XCD-affine, paired w/ k_final).
#define FN_CH3 1107   // ceil(NFACE*4/256)
__global__ __launch_bounds__(256) void k_fn(const float* __restrict__ shpT, const int* __restrict__ tri,
                                            h4* __restrict__ fq, int lo) {
  int g = blockIdx.x;
  int xcd = g & 7, chunk = g >> 3;
  int bt8 = lo + xcd;
  int t = threadIdx.x;
  int bp = t & 3, foff = t >> 2;
  int f = chunk * 64 + foff;
  if (f >= NFACE) return;
  int i0 = tri[f * 3 + 0] - 1;
  int i1 = tri[f * 3 + 1] - 1;
  int i2 = tri[f * 3 + 2] - 1;
  const float* sl = shpT + (size_t)bt8 * (size_t)(NV3 * 8) + 2 * bp;
  int a0 = i0 * 24, a1 = i1 * 24, a2 = i2 * 24;
  f2 x1 = *(const f2*)(sl + a0), y1 = *(const f2*)(sl + a0 + 8), z1 = *(const f2*)(sl + a0 + 16);
  f2 x2 = *(const f2*)(sl + a1), y2 = *(const f2*)(sl + a1 + 8), z2 = *(const f2*)(sl + a1 + 16);
  f2 x3 = *(const f2*)(sl + a2), y3 = *(const f2*)(sl + a2 + 8), z3 = *(const f2*)(sl + a2 + 16);
  f2 e1x = x1 - x2, e1y = y1 - y2, e1z = z1 - z2;
  f2 e2x = x2 - x3, e2y = y2 - y3, e2z = z2 - z3;
  f2 cx = e1y * e2z - e1z * e2y;
  f2 cy = e1z * e2x - e1x * e2z;
  f2 cz = e1x * e2y - e1y * e2x;
  h8 st;
  st[0] = (_Float16)cx.x; st[1] = (_Float16)cy.x; st[2] = (_Float16)cz.x; st[3] = (_Float16)0.f;
  st[4] = (_Float16)cx.y; st[5] = (_Float16)cy.y; st[6] = (_Float16)cz.y; st[7] = (_Float16)0.f;
  *(h8*)(fq + (size_t)bt8 * (size_t)(NFACE * 8) + (size_t)f * 8 + 2 * bp) = st;   // cached: L2-hot for paired k_final
}

// K4: face_color, bi-PAIR threads: 8x 16 B fq gathers + 3 shared u32 tex loads serve
// TWO outputs. Rotate-normal + SH per lane-pair; out via LDS transpose tile (64 v/block).
#define FI_CH3 558    // ceil(NVERT*4/256)
__global__ __launch_bounds__(256) void k_final(const u16* __restrict__ texT, const h4* __restrict__ fq,
                                               const int* __restrict__ pbuf, const float* __restrict__ mpad,
                                               const float* __restrict__ G, float* __restrict__ out, int lo) {
  __shared__ float scol[8][200];   // [bi][voff*3+d] for 64 verts, pad 192->200
  int g = blockIdx.x;
  int xcd = g & 7, chunk = g >> 3;
  int bt8 = lo + xcd;
  int t = threadIdx.x;
  int bp = t & 3, voff = t >> 2;
  int v0 = chunk * 64;
  int v = v0 + voff;
  int vc = v < NVERT ? v : NVERT - 1;
  bool valid = v < NVERT;
  i4 p0 = *(const i4*)(pbuf + (size_t)vc * 8);
  i4 p1 = *(const i4*)(pbuf + (size_t)vc * 8 + 4);
  int idx[8] = {p0.x, p0.y, p0.z, p0.w, p1.x, p1.y, p1.z, p1.w};
  const h4* fb = fq + (size_t)bt8 * (size_t)(NFACE * 8) + 2 * bp;
  float vx0 = 0.f, vy0 = 0.f, vz0 = 0.f, vx1 = 0.f, vy1 = 0.f, vz1 = 0.f;
#pragma unroll
  for (int i = 0; i < 8; i++) {
    int id = idx[i] - 1;               // in [0, NFACE]; NFACE == zero contribution
    if (id < NFACE) {
      h8 q = *(const h8*)(fb + (size_t)id * 8);
      vx0 += (float)q[0]; vy0 += (float)q[1]; vz0 += (float)q[2];
      vx1 += (float)q[4]; vy1 += (float)q[5]; vz1 += (float)q[6];
    }
  }
  // tex: 3 u32 loads cover both bi of the pair
  const u16* tp = texT + (size_t)bt8 * (size_t)(NV3 * 8) + (size_t)vc * 24 + 2 * bp;
  u32 t0 = *(const u32*)(tp);
  u32 t1 = *(const u32*)(tp + 8);
  u32 t2 = *(const u32*)(tp + 16);
  const float kc1 = 1.7724539f;             // a1*c1 = sqrt(pi)
  const float kc2 = 2.4270324f;             // a2*c2
  const float kd0 = 0.28867513f;            // 0.5/sqrt(3)
#pragma unroll
  for (int pp = 0; pp < 2; pp++) {
    int bi = 2 * bp + pp;
    int b = bt8 * 8 + bi;
    float vx = pp ? vx1 : vx0, vy = pp ? vy1 : vy0, vz = pp ? vz1 : vz0;
    float n2 = vx * vx + vy * vy + vz * vz;
    float inv = rsqrtf(fmaxf(n2, 1e-30f));
    vx *= inv; vy *= inv; vz *= inv;
    const float* mp = mpad + b * 12;
    f4 m0 = *(const f4*)mp;
    f4 m1 = *(const f4*)(mp + 4);
    float m8 = mp[8];
    float nx = vx * m0.x + vy * m0.y + vz * m0.z;
    float ny = vx * m0.w + vy * m1.x + vz * m1.y;
    float nz = vx * m1.z + vy * m1.w + vz * m8;
    float Y[9];
    Y[0] = 0.8862269f;                      // a0*c0
    Y[1] = -kc1 * ny;
    Y[2] = kc1 * nz;
    Y[3] = -kc1 * nx;
    Y[4] = kc2 * nx * ny;
    Y[5] = -kc2 * ny * nz;
    Y[6] = kc2 * kd0 * (3.f * nz * nz - 1.f);
    Y[7] = -kc2 * nx * nz;
    Y[8] = kc2 * 0.5f * (nx * nx - ny * ny);
    const float* gg = G + b * 27;
    float gv[28];
#pragma unroll
    for (int q = 0; q < 7; q++) {
      f4 g4 = ld4u(gg + q * 4);
      gv[q * 4] = g4.x; gv[q * 4 + 1] = g4.y; gv[q * 4 + 2] = g4.z; gv[q * 4 + 3] = g4.w;
    }
    float tc[3];
    tc[0] = b2f((u16)(pp ? (t0 >> 16) : t0));
    tc[1] = b2f((u16)(pp ? (t1 >> 16) : t1));
    tc[2] = b2f((u16)(pp ? (t2 >> 16) : t2));
    if (valid) {
#pragma unroll
      for (int d = 0; d < 3; d++) {
        float L = 0.f;
#pragma unroll
        for (int cc = 0; cc < 9; cc++) L += Y[cc] * gv[cc * 3 + d];
        scol[bi][voff * 3 + d] = tc[d] * L;
      }
    }
  }
  __syncthreads();
  int nvv = NVERT - v0;
  int lim = (nvv < 64 ? nvv : 64) * 3;
  size_t base = (size_t)(bt8 * 8) * NV3 + (size_t)v0 * 3;
#pragma unroll
  for (int it = 0; it < 6; it++) {
    int l = it * 256 + t;                  // 0..1535 = 8 batches x 192 elems
    int b2 = l / 192, e = l - b2 * 192;
    if (e < lim) {
      size_t o = base + (size_t)b2 * NV3 + e;
      __builtin_nontemporal_store(scol[b2][e], out + o);
    }
  }
}

// K5: landmarks — recompute shape_t at 68 kp verts from shpT, project (f32 out).
__global__ __launch_bounds__(128) void k_lms(const float* __restrict__ shpT, const int* __restrict__ kp,
                                             const float* __restrict__ mpad, float* __restrict__ out) {
  int t = threadIdx.x;
  int b = blockIdx.x;
  if (t >= 68) return;
  int v = kp[t];
  const float* sl = shpT + (size_t)(b >> 3) * (size_t)(NV3 * 8) + (size_t)v * 24 + (b & 7);
  float sx = sl[0], sy = sl[8], sz = sl[16];
  const float* mp = mpad + b * 12;
  f4 m0 = *(const f4*)mp;
  f4 m1 = *(const f4*)(mp + 4);
  f4 m2 = *(const f4*)(mp + 8);
  float ox = sx * m0.x + sy * m0.y + sz * m0.z + m2.y;
  float oy = sx * m0.w + sy * m1.x + sz * m1.y + m2.z;
  float oz = sx * m1.z + sy * m1.w + sz * m2.x + m2.w;
  float w = 10.f - oz;                      // pts@[1,1,-1] + [0,0,10]
  float invw = 1.0f / w;
  float lx = 1015.f * ox * invw + 128.f;    // FOCAL*x/w + half
  float ly = 1015.f * oy * invw + 128.f;
  size_t o = LMS_BASE + ((size_t)b * 68 + t) * 2;
  out[o + 0] = lx;
  out[o + 1] = 256.f - ly;                  // IMG - y
}

extern "C" void kernel_launch(void* const* d_in, const int* in_sizes, int n_in,
                              void* d_out, int out_size, void* d_ws, size_t ws_size,
                              hipStream_t stream) {
  const float* coeff     = (const float*)d_in[0];
  const float* meanshape = (const float*)d_in[1];
  const float* idB       = (const float*)d_in[2];
  const float* exB       = (const float*)d_in[3];
  const float* meantex   = (const float*)d_in[4];
  const float* txB       = (const float*)d_in[5];
  const int* tri         = (const int*)d_in[6];
  const int* pbuf        = (const int*)d_in[7];
  const int* kp          = (const int*)d_in[8];
  float* out = (float*)d_out;
  char* ws = (char*)d_ws;
  float* shpT = (float*)(ws + SHAPE_OFF);
  u16* texT   = (u16*)(ws + TEX_OFF);
  h4* fq      = (h4*)(ws + FQ_OFF);
  u16* cpack  = (u16*)(ws + CPACK_OFF);
  float* mpad = (float*)(ws + MPAD_OFF);
  float* G    = (float*)(ws + GG_OFF);
  float* mean = (float*)(ws + MEAN_OFF);
  float* part = (float*)(ws + PART_OFF);

  k_mean<<<64, 256, 0, stream>>>(meanshape, part);
  k_params<<<1, 128, 0, stream>>>(coeff, cpack, mpad, G, part, mean);
  k_gemmS<<<2 * SBLK, 256, 0, stream>>>(idB, exB, meanshape, cpack, mean, mpad, shpT, out);
  k_gemmT<<<2 * SBLK, 256, 0, stream>>>(txB, meantex, cpack, texT);
  for (int lo = 0; lo < 16; lo += 8) {
    k_fn<<<8 * FN_CH3, 256, 0, stream>>>(shpT, tri, fq, lo);
    k_final<<<8 * FI_CH3, 256, 0, stream>>>(texT, fq, pbuf, mpad, G, out, lo);
  }
  k_lms<<<128, 128, 0, stream>>>(shpT, kp, mpad, out);
}